// Round 2
// baseline (246.790 us; speedup 1.0000x reference)
//
#include <hip/hip_runtime.h>
#include <stdint.h>
#include <math.h>

#define NTH 64
#define CAP 1024           // max candidates per class (M ~ 440 expected, huge margin)
#define SLOTS 16           // CAP / 64 register slots per lane
#define MAXK 50
#define THRESH_F 0.05f
#define NMS_T 0.3f

// Decode one (image b, row n, class c) box exactly like the reference:
// bbox_transform_inv + clip + /scale.  (Identical arithmetic to the version
// that passed with absmax 0.0 -- do not reorder.)
__device__ __forceinline__ void decode_box(
    const float* __restrict__ rois, const float* __restrict__ pred,
    float H, float W, float scale,
    int b, int n, int c, int N, int C, float out[4])
{
    const float* r = rois + ((size_t)b * N + n) * 5;
    float bx1 = r[1], by1 = r[2], bx2 = r[3], by2 = r[4];
    float w  = bx2 - bx1 + 1.0f;
    float h  = by2 - by1 + 1.0f;
    float cx = bx1 + 0.5f * w;
    float cy = by1 + 0.5f * h;
    const float* d = pred + ((size_t)b * N + n) * 4 * C + 4 * c;
    float dx = d[0] * 0.1f, dy = d[1] * 0.1f;
    float dw = d[2] * 0.2f, dh = d[3] * 0.2f;
    float pcx = dx * w + cx;
    float pcy = dy * h + cy;
    float pw  = expf(dw) * w;
    float ph  = expf(dh) * h;
    float X1 = fminf(fmaxf(pcx - 0.5f * pw, 0.0f), W - 1.0f);
    float Y1 = fminf(fmaxf(pcy - 0.5f * ph, 0.0f), H - 1.0f);
    float X2 = fminf(fmaxf(pcx + 0.5f * pw, 0.0f), W - 1.0f);
    float Y2 = fminf(fmaxf(pcy + 0.5f * ph, 0.0f), H - 1.0f);
    out[0] = X1 / scale;
    out[1] = Y1 / scale;
    out[2] = X2 / scale;
    out[3] = Y2 / scale;
}

// Kernel 1: ONE WAVE per (stream, image, fg-class).  Sort-free, barrier-free
// greedy NMS by iterative argmax over 64-bit keys (score_bits<<32 | ~slot),
// candidates held in registers (SLOTS per lane), keeper box broadcast via a
// uniform-address LDS read.  Slots are assigned in row order (ballot-prefix
// compaction), so key order == reference argsort(-score) stable order.
__global__ __launch_bounds__(NTH) void nms_kernel(
    const float* __restrict__ rois_A, const float* __restrict__ cls_A,
    const float* __restrict__ pred_A, const float* __restrict__ info_A,
    const float* __restrict__ rois_B, const float* __restrict__ cls_B,
    const float* __restrict__ pred_B, const float* __restrict__ info_B,
    int Bimg, int N, int C,
    float* __restrict__ kept_scores, int* __restrict__ kcounts,
    float* __restrict__ cls_box, int* __restrict__ sync_counter)
{
    const int FG = C - 1;
    const int bx = blockIdx.x;
    const int st  = bx / (Bimg * FG);
    const int rem = bx % (Bimg * FG);
    const int b = rem / FG;
    const int j = rem % FG;
    const int c = j + 1;
    const int lane = threadIdx.x;

    if (bx == 0 && lane == 0) *sync_counter = 0;  // for select_combine

    const float* rois = st ? rois_B : rois_A;
    const float* cls  = st ? cls_B  : cls_A;
    const float* pred = st ? pred_B : pred_A;
    const float* info = st ? info_B : info_A;

    __shared__ unsigned short rowsL[CAP];
    __shared__ float scL[CAP];
    __shared__ float4 boxL[CAP];

    // ---- Collect: ballot-prefix compaction (slot order == row order) ----
    int cnt = 0;
    #pragma unroll 4
    for (int base = 0; base < N; base += 64) {
        const int n = base + lane;
        float sc = 0.0f;
        if (n < N) sc = cls[((size_t)b * N + n) * C + c];
        const bool val = sc > THRESH_F;
        const uint64_t bal = __ballot(val);
        if (val) {
            const int slot = cnt + __popcll(bal & ((1ull << lane) - 1ull));
            if (slot < CAP) { rowsL[slot] = (unsigned short)n; scL[slot] = sc; }
        }
        cnt += __popcll(bal);
    }
    const int M = cnt < CAP ? cnt : CAP;
    __syncthreads();   // single-wave block: cheap; orders LDS w->r across lanes

    // ---- Decode all M candidates into register slots + LDS mirror ----
    const float H = info[b * 3 + 0];
    const float W = info[b * 3 + 1];
    const float scale = info[b * 3 + 2];
    uint64_t key[SLOTS];
    float x1[SLOTS], y1[SLOTS], x2[SLOTS], y2[SLOTS], ar[SLOTS];
    #pragma unroll
    for (int s = 0; s < SLOTS; ++s) {
        key[s] = 0ull;
        const int slot = s * 64 + lane;
        if (slot < M) {
            const int n = rowsL[slot];
            float o[4];
            decode_box(rois, pred, H, W, scale, b, n, c, N, C, o);
            x1[s] = o[0]; y1[s] = o[1]; x2[s] = o[2]; y2[s] = o[3];
            ar[s] = (o[2] - o[0] + 1.0f) * (o[3] - o[1] + 1.0f);
            boxL[slot] = make_float4(o[0], o[1], o[2], o[3]);
            key[s] = ((uint64_t)__float_as_uint(scL[slot]) << 32) |
                     (uint32_t)(~(uint32_t)slot);
        }
    }
    __syncthreads();

    // ---- Greedy NMS: iterative argmax, all in registers, no barriers ----
    int kept = 0;
    float mysc = 0.0f;
    float4 cb = make_float4(0.f, 0.f, 0.f, 0.f);
    #pragma unroll 1
    for (int k = 0; k < MAXK; ++k) {
        uint64_t lm = 0ull;
        #pragma unroll
        for (int s = 0; s < SLOTS; ++s) {
            if (s * 64 >= M) break;              // uniform early-out
            if (key[s] > lm) lm = key[s];
        }
        #pragma unroll
        for (int m = 1; m < 64; m <<= 1) {
            const uint64_t o = __shfl_xor(lm, m);
            if (o > lm) lm = o;
        }
        if (lm == 0ull) break;                   // uniform: no candidates left

        const int slot = (int)(~(uint32_t)lm);   // winner slot (uniform value)
        const float4 kb = boxL[slot];            // broadcast read
        const float kar = (kb.z - kb.x + 1.0f) * (kb.w - kb.y + 1.0f);
        if (lane == kept) mysc = __uint_as_float((uint32_t)(lm >> 32));
        if (kept == 0) cb = kb;                  // rank-0 keep = class best

        #pragma unroll
        for (int s = 0; s < SLOTS; ++s) {
            if (s * 64 >= M) break;
            if (key[s] != 0ull) {
                const float ix1 = fmaxf(kb.x, x1[s]);
                const float iy1 = fmaxf(kb.y, y1[s]);
                const float ix2 = fminf(kb.z, x2[s]);
                const float iy2 = fminf(kb.w, y2[s]);
                const float iw = fmaxf(ix2 - ix1 + 1.0f, 0.0f);
                const float ih = fmaxf(iy2 - iy1 + 1.0f, 0.0f);
                const float inter = iw * ih;
                const float iou = inter / (kar + ar[s] - inter);
                if (iou > NMS_T) key[s] = 0ull;  // keeper self-suppresses (iou=1)
            }
        }
        kept++;
    }

    // ---- Flush ----
    const size_t obase = (size_t)(st * Bimg + b) * FG + j;
    if (lane < kept) kept_scores[obase * MAXK + lane] = mysc;
    if (lane == 0) {
        kcounts[obase] = kept;
        float* cbp = cls_box + obase * 4;
        cbp[0] = cb.x; cbp[1] = cb.y; cbp[2] = cb.z; cbp[3] = cb.w;
    }
}

// Kernel 2: one block per (stream, image): global top-50 cap via exact counted
// comparison (score desc, class asc on ties), then the LAST finished block
// performs the joint A*B argmax + output gather (device-scope atomic gate).
__global__ __launch_bounds__(NTH) void select_combine(
    const float* __restrict__ kept_scores, const int* __restrict__ kcounts,
    const float* __restrict__ cls_box,
    const float* __restrict__ rois_A, const float* __restrict__ pred_A,
    const float* __restrict__ info_A,
    const float* __restrict__ rois_B, const float* __restrict__ pred_B,
    const float* __restrict__ info_B,
    int Bimg, int N, int C,
    float* best_s, float* best_b, int* sync_counter, float* __restrict__ out)
{
    const int FG = C - 1;
    const int bx = blockIdx.x;           // st*Bimg + b
    const int st = bx / Bimg;
    const int b  = bx % Bimg;
    const int tid = threadIdx.x;

    __shared__ float sk[20][MAXK];
    __shared__ int   skc[20];
    __shared__ float stopv[20];
    __shared__ int   inflag[20];
    __shared__ float gbox[4];
    __shared__ int   amlast;

    const size_t base = (size_t)bx * FG;
    for (int i = tid; i < FG * MAXK; i += NTH)
        sk[i / MAXK][i % MAXK] = kept_scores[base * MAXK + i];
    if (tid < FG) skc[tid] = kcounts[base + tid];
    __syncthreads();

    if (tid < FG) {
        const int cc = tid;
        const int kc = skc[cc];
        const float sc = (kc > 0) ? sk[cc][0] : -INFINITY;
        stopv[cc] = sc;
        int cnt2 = 0;
        if (kc > 0) {
            for (int c2 = 0; c2 < FG && cnt2 < MAXK; ++c2) {
                const int k2 = skc[c2];
                for (int k = 0; k < k2; ++k) {
                    const float v = sk[c2][k];
                    const bool greater = (v > sc) || (v == sc && c2 < cc);
                    if (!greater) break;   // lists are non-increasing
                    if (++cnt2 >= MAXK) break;
                }
            }
        }
        inflag[tid] = (kc > 0 && cnt2 < MAXK) ? 1 : 0;
    }
    __syncthreads();

    if (tid == 0) {
        int g = -1;
        float bs = -INFINITY;
        for (int c2 = 0; c2 < FG; ++c2)
            if (skc[c2] > 0 && stopv[c2] > bs) { bs = stopv[c2]; g = c2; }
        if (g >= 0) {
            const float* cbp = cls_box + (base + g) * 4;
            gbox[0] = cbp[0]; gbox[1] = cbp[1]; gbox[2] = cbp[2]; gbox[3] = cbp[3];
        } else {
            const float* rois = st ? rois_B : rois_A;
            const float* pred = st ? pred_B : pred_A;
            const float* info = st ? info_B : info_A;
            decode_box(rois, pred, info[b * 3], info[b * 3 + 1], info[b * 3 + 2],
                       b, 0, 1, N, C, gbox);
        }
    }
    __syncthreads();

    if (tid < FG) {
        const int in = inflag[tid];
        best_s[base + tid] = in ? stopv[tid] : -INFINITY;
        float* ob = best_b + (base + tid) * 4;
        if (in) {
            const float* cbp = cls_box + (base + tid) * 4;
            ob[0] = cbp[0]; ob[1] = cbp[1]; ob[2] = cbp[2]; ob[3] = cbp[3];
        } else {
            ob[0] = gbox[0]; ob[1] = gbox[1]; ob[2] = gbox[2]; ob[3] = gbox[3];
        }
    }

    // ---- last-done block performs the combine ----
    __threadfence();
    if (tid == 0) amlast = (atomicAdd(sync_counter, 1) == 2 * Bimg - 1);
    __syncthreads();
    if (amlast) {
        __threadfence();   // acquire: other blocks' best_s/best_b now visible
        if (tid < Bimg) {
            const int i = tid;
            const float* sA = best_s + (size_t)i * FG;
            const float* sB = best_s + (size_t)(Bimg + i) * FG;
            float bj = 0.0f;
            int cls = 0;
            for (int cc = 0; cc < FG; ++cc) {
                const float v = sA[cc] * sB[cc];   // IEEE: -inf*-inf=+inf
                if (cc == 0 || v > bj) { bj = v; cls = cc; }
            }
            const float* bA = best_b + ((size_t)i * FG + cls) * 4;
            const float* bB = best_b + ((size_t)(Bimg + i) * FG + cls) * 4;
            for (int k = 0; k < 4; ++k) {
                out[i * 4 + k]            = bA[k];
                out[Bimg * 4 + i * 4 + k] = bB[k];
            }
        }
    }
}

extern "C" void kernel_launch(void* const* d_in, const int* in_sizes, int n_in,
                              void* d_out, int out_size, void* d_ws, size_t ws_size,
                              hipStream_t stream) {
    const float* rois_A = (const float*)d_in[0];
    const float* cls_A  = (const float*)d_in[1];
    const float* pred_A = (const float*)d_in[2];
    const float* info_A = (const float*)d_in[3];
    const float* rois_B = (const float*)d_in[4];
    const float* cls_B  = (const float*)d_in[5];
    const float* pred_B = (const float*)d_in[6];
    const float* info_B = (const float*)d_in[7];
    float* out = (float*)d_out;

    const int Bimg = in_sizes[3] / 3;                  // 8
    const int N    = in_sizes[0] / (Bimg * 5);         // 2000
    const int C    = in_sizes[1] / (Bimg * N);         // 21
    const int FG   = C - 1;                            // 20
    const int NSB  = 2 * Bimg * FG;                    // 320 tasks

    char* ws = (char*)d_ws;
    int* sync_counter = (int*)ws;
    size_t off = 16;
    float* kept_scores = (float*)(ws + off);               // [2][B][FG][50]
    off += (size_t)NSB * MAXK * sizeof(float);
    int* kcounts = (int*)(ws + off);                       // [2][B][FG]
    off += (size_t)NSB * sizeof(int);
    float* cls_box = (float*)(ws + off);                   // [2][B][FG][4]
    off += (size_t)NSB * 4 * sizeof(float);
    float* best_s = (float*)(ws + off);                    // [2][B][FG]
    off += (size_t)NSB * sizeof(float);
    float* best_b = (float*)(ws + off);                    // [2][B][FG][4]

    nms_kernel<<<NSB, NTH, 0, stream>>>(
        rois_A, cls_A, pred_A, info_A,
        rois_B, cls_B, pred_B, info_B,
        Bimg, N, C, kept_scores, kcounts, cls_box, sync_counter);

    select_combine<<<2 * Bimg, NTH, 0, stream>>>(
        kept_scores, kcounts, cls_box,
        rois_A, pred_A, info_A, rois_B, pred_B, info_B,
        Bimg, N, C, best_s, best_b, sync_counter, out);
}

// Round 3
// 117.888 us; speedup vs baseline: 2.0934x; 2.0934x over previous
//
#include <hip/hip_runtime.h>
#include <stdint.h>
#include <math.h>

#define NTH 64
#define CAP 1024           // max candidates per class (M ~ 330 expected, +20 sigma margin)
#define SLOTS 16           // CAP / 64 register slots per lane
#define MAXK 50
#define THRESH_F 0.05f
#define NMS_T 0.3f

// Decode one (image b, row n, class c) box exactly like the reference:
// bbox_transform_inv + clip + /scale.  (Identical arithmetic to the version
// that passed with absmax 0.0 -- do not reorder.)
__device__ __forceinline__ void decode_box(
    const float* __restrict__ rois, const float* __restrict__ pred,
    float H, float W, float scale,
    int b, int n, int c, int N, int C, float out[4])
{
    const float* r = rois + ((size_t)b * N + n) * 5;
    float bx1 = r[1], by1 = r[2], bx2 = r[3], by2 = r[4];
    float w  = bx2 - bx1 + 1.0f;
    float h  = by2 - by1 + 1.0f;
    float cx = bx1 + 0.5f * w;
    float cy = by1 + 0.5f * h;
    const float* d = pred + ((size_t)b * N + n) * 4 * C + 4 * c;
    float dx = d[0] * 0.1f, dy = d[1] * 0.1f;
    float dw = d[2] * 0.2f, dh = d[3] * 0.2f;
    float pcx = dx * w + cx;
    float pcy = dy * h + cy;
    float pw  = expf(dw) * w;
    float ph  = expf(dh) * h;
    float X1 = fminf(fmaxf(pcx - 0.5f * pw, 0.0f), W - 1.0f);
    float Y1 = fminf(fmaxf(pcy - 0.5f * ph, 0.0f), H - 1.0f);
    float X2 = fminf(fmaxf(pcx + 0.5f * pw, 0.0f), W - 1.0f);
    float Y2 = fminf(fmaxf(pcy + 0.5f * ph, 0.0f), H - 1.0f);
    out[0] = X1 / scale;
    out[1] = Y1 / scale;
    out[2] = X2 / scale;
    out[3] = Y2 / scale;
}

// Kernel 1: ONE WAVE per (stream, image, fg-class).  Sort-free greedy NMS by
// iterative argmax over 64-bit keys (score_bits<<32 | ~slot), candidate state
// in registers (SLOTS per lane, ALL slot loops statically unrolled -- no
// runtime breaks, so nothing lands in scratch).  Keeper box broadcast via a
// uniform-address LDS read.  Slots assigned in row order (ballot-prefix
// compaction) => key order == reference argsort(-score) stable order.
__global__ __launch_bounds__(NTH, 1) void nms_kernel(
    const float* __restrict__ rois_A, const float* __restrict__ cls_A,
    const float* __restrict__ pred_A, const float* __restrict__ info_A,
    const float* __restrict__ rois_B, const float* __restrict__ cls_B,
    const float* __restrict__ pred_B, const float* __restrict__ info_B,
    int Bimg, int N, int C,
    float* __restrict__ kept_scores, int* __restrict__ kcounts,
    float* __restrict__ cls_box, int* __restrict__ sync_counter)
{
    const int FG = C - 1;
    const int bx = blockIdx.x;
    const int st  = bx / (Bimg * FG);
    const int rem = bx % (Bimg * FG);
    const int b = rem / FG;
    const int j = rem % FG;
    const int c = j + 1;
    const int lane = threadIdx.x;

    if (bx == 0 && lane == 0) *sync_counter = 0;  // for select_combine

    const float* rois = st ? rois_B : rois_A;
    const float* cls  = st ? cls_B  : cls_A;
    const float* pred = st ? pred_B : pred_A;
    const float* info = st ? info_B : info_A;

    __shared__ unsigned short rowsL[CAP];
    __shared__ float scL[CAP];
    __shared__ float4 boxL[CAP];

    // ---- Collect: ballot-prefix compaction (slot order == row order) ----
    int cnt = 0;
    for (int base = 0; base < N; base += 64) {
        const int n = base + lane;
        float sc = 0.0f;
        if (n < N) sc = cls[((size_t)b * N + n) * C + c];
        const bool val = sc > THRESH_F;
        const uint64_t bal = __ballot(val);
        if (val) {
            const int slot = cnt + __popcll(bal & ((1ull << lane) - 1ull));
            if (slot < CAP) { rowsL[slot] = (unsigned short)n; scL[slot] = sc; }
        }
        cnt += __popcll(bal);
    }
    const int M = cnt < CAP ? cnt : CAP;
    __syncthreads();   // single-wave block: cheap; orders LDS w->r across lanes

    // ---- Decode all M candidates into register slots + LDS mirror ----
    const float H = info[b * 3 + 0];
    const float W = info[b * 3 + 1];
    const float scale = info[b * 3 + 2];
    uint64_t key[SLOTS];
    float x1[SLOTS], y1[SLOTS], x2[SLOTS], y2[SLOTS], ar[SLOTS];
    #pragma unroll
    for (int s = 0; s < SLOTS; ++s) {
        key[s] = 0ull;
        x1[s] = 0.f; y1[s] = 0.f; x2[s] = 0.f; y2[s] = 0.f; ar[s] = 0.f;
        const int slot = s * 64 + lane;
        if (slot < M) {
            const int n = rowsL[slot];
            float o[4];
            decode_box(rois, pred, H, W, scale, b, n, c, N, C, o);
            x1[s] = o[0]; y1[s] = o[1]; x2[s] = o[2]; y2[s] = o[3];
            ar[s] = (o[2] - o[0] + 1.0f) * (o[3] - o[1] + 1.0f);
            boxL[slot] = make_float4(o[0], o[1], o[2], o[3]);
            key[s] = ((uint64_t)__float_as_uint(scL[slot]) << 32) |
                     (uint32_t)(~(uint32_t)slot);
        }
    }
    __syncthreads();

    // ---- Greedy NMS: iterative argmax, registers only, no barriers ----
    int kept = 0;
    float mysc = 0.0f;
    float4 cb = make_float4(0.f, 0.f, 0.f, 0.f);
    #pragma unroll 1
    for (int k = 0; k < MAXK; ++k) {
        uint64_t lm = 0ull;
        #pragma unroll
        for (int s = 0; s < SLOTS; ++s) {        // static unroll, no break
            if (key[s] > lm) lm = key[s];
        }
        #pragma unroll
        for (int m = 1; m < 64; m <<= 1) {
            const uint64_t o = __shfl_xor(lm, m);
            if (o > lm) lm = o;
        }
        if (lm == 0ull) break;                   // uniform: no candidates left

        const int slot = (int)(~(uint32_t)lm);   // winner slot (uniform value)
        const float4 kb = boxL[slot];            // broadcast read
        const float kar = (kb.z - kb.x + 1.0f) * (kb.w - kb.y + 1.0f);
        if (lane == kept) mysc = __uint_as_float((uint32_t)(lm >> 32));
        if (kept == 0) cb = kb;                  // rank-0 keep = class best

        #pragma unroll
        for (int s = 0; s < SLOTS; ++s) {        // static unroll, predicated
            if (key[s] != 0ull) {                // dead slots: execz fast path
                const float ix1 = fmaxf(kb.x, x1[s]);
                const float iy1 = fmaxf(kb.y, y1[s]);
                const float ix2 = fminf(kb.z, x2[s]);
                const float iy2 = fminf(kb.w, y2[s]);
                const float iw = fmaxf(ix2 - ix1 + 1.0f, 0.0f);
                const float ih = fmaxf(iy2 - iy1 + 1.0f, 0.0f);
                const float inter = iw * ih;
                const float iou = inter / (kar + ar[s] - inter);
                if (iou > NMS_T) key[s] = 0ull;  // keeper self-suppresses (iou=1)
            }
        }
        kept++;
    }

    // ---- Flush ----
    const size_t obase = (size_t)(st * Bimg + b) * FG + j;
    if (lane < kept) kept_scores[obase * MAXK + lane] = mysc;
    if (lane == 0) {
        kcounts[obase] = kept;
        float* cbp = cls_box + obase * 4;
        cbp[0] = cb.x; cbp[1] = cb.y; cbp[2] = cb.z; cbp[3] = cb.w;
    }
}

// Kernel 2: one block per (stream, image): global top-50 cap via exact counted
// comparison (score desc, class asc on ties), then the LAST finished block
// performs the joint A*B argmax + output gather (device-scope atomic gate).
__global__ __launch_bounds__(NTH) void select_combine(
    const float* __restrict__ kept_scores, const int* __restrict__ kcounts,
    const float* __restrict__ cls_box,
    const float* __restrict__ rois_A, const float* __restrict__ pred_A,
    const float* __restrict__ info_A,
    const float* __restrict__ rois_B, const float* __restrict__ pred_B,
    const float* __restrict__ info_B,
    int Bimg, int N, int C,
    float* best_s, float* best_b, int* sync_counter, float* __restrict__ out)
{
    const int FG = C - 1;
    const int bx = blockIdx.x;           // st*Bimg + b
    const int st = bx / Bimg;
    const int b  = bx % Bimg;
    const int tid = threadIdx.x;

    __shared__ float sk[20][MAXK];
    __shared__ int   skc[20];
    __shared__ float stopv[20];
    __shared__ int   inflag[20];
    __shared__ float gbox[4];
    __shared__ int   amlast;

    const size_t base = (size_t)bx * FG;
    for (int i = tid; i < FG * MAXK; i += NTH)
        sk[i / MAXK][i % MAXK] = kept_scores[base * MAXK + i];
    if (tid < FG) skc[tid] = kcounts[base + tid];
    __syncthreads();

    if (tid < FG) {
        const int cc = tid;
        const int kc = skc[cc];
        const float sc = (kc > 0) ? sk[cc][0] : -INFINITY;
        stopv[cc] = sc;
        int cnt2 = 0;
        if (kc > 0) {
            for (int c2 = 0; c2 < FG && cnt2 < MAXK; ++c2) {
                const int k2 = skc[c2];
                for (int k = 0; k < k2; ++k) {
                    const float v = sk[c2][k];
                    const bool greater = (v > sc) || (v == sc && c2 < cc);
                    if (!greater) break;   // lists are non-increasing
                    if (++cnt2 >= MAXK) break;
                }
            }
        }
        inflag[tid] = (kc > 0 && cnt2 < MAXK) ? 1 : 0;
    }
    __syncthreads();

    if (tid == 0) {
        int g = -1;
        float bs = -INFINITY;
        for (int c2 = 0; c2 < FG; ++c2)
            if (skc[c2] > 0 && stopv[c2] > bs) { bs = stopv[c2]; g = c2; }
        if (g >= 0) {
            const float* cbp = cls_box + (base + g) * 4;
            gbox[0] = cbp[0]; gbox[1] = cbp[1]; gbox[2] = cbp[2]; gbox[3] = cbp[3];
        } else {
            const float* rois = st ? rois_B : rois_A;
            const float* pred = st ? pred_B : pred_A;
            const float* info = st ? info_B : info_A;
            decode_box(rois, pred, info[b * 3], info[b * 3 + 1], info[b * 3 + 2],
                       b, 0, 1, N, C, gbox);
        }
    }
    __syncthreads();

    if (tid < FG) {
        const int in = inflag[tid];
        best_s[base + tid] = in ? stopv[tid] : -INFINITY;
        float* ob = best_b + (base + tid) * 4;
        if (in) {
            const float* cbp = cls_box + (base + tid) * 4;
            ob[0] = cbp[0]; ob[1] = cbp[1]; ob[2] = cbp[2]; ob[3] = cbp[3];
        } else {
            ob[0] = gbox[0]; ob[1] = gbox[1]; ob[2] = gbox[2]; ob[3] = gbox[3];
        }
    }

    // ---- last-done block performs the combine ----
    __threadfence();
    if (tid == 0) amlast = (atomicAdd(sync_counter, 1) == 2 * Bimg - 1);
    __syncthreads();
    if (amlast) {
        __threadfence();   // acquire: other blocks' best_s/best_b now visible
        if (tid < Bimg) {
            const int i = tid;
            const float* sA = best_s + (size_t)i * FG;
            const float* sB = best_s + (size_t)(Bimg + i) * FG;
            float bj = 0.0f;
            int cls = 0;
            for (int cc = 0; cc < FG; ++cc) {
                const float v = sA[cc] * sB[cc];   // IEEE: -inf*-inf=+inf
                if (cc == 0 || v > bj) { bj = v; cls = cc; }
            }
            const float* bA = best_b + ((size_t)i * FG + cls) * 4;
            const float* bB = best_b + ((size_t)(Bimg + i) * FG + cls) * 4;
            for (int k = 0; k < 4; ++k) {
                out[i * 4 + k]            = bA[k];
                out[Bimg * 4 + i * 4 + k] = bB[k];
            }
        }
    }
}

extern "C" void kernel_launch(void* const* d_in, const int* in_sizes, int n_in,
                              void* d_out, int out_size, void* d_ws, size_t ws_size,
                              hipStream_t stream) {
    const float* rois_A = (const float*)d_in[0];
    const float* cls_A  = (const float*)d_in[1];
    const float* pred_A = (const float*)d_in[2];
    const float* info_A = (const float*)d_in[3];
    const float* rois_B = (const float*)d_in[4];
    const float* cls_B  = (const float*)d_in[5];
    const float* pred_B = (const float*)d_in[6];
    const float* info_B = (const float*)d_in[7];
    float* out = (float*)d_out;

    const int Bimg = in_sizes[3] / 3;                  // 8
    const int N    = in_sizes[0] / (Bimg * 5);         // 2000
    const int C    = in_sizes[1] / (Bimg * N);         // 21
    const int FG   = C - 1;                            // 20
    const int NSB  = 2 * Bimg * FG;                    // 320 tasks

    char* ws = (char*)d_ws;
    int* sync_counter = (int*)ws;
    size_t off = 16;
    float* kept_scores = (float*)(ws + off);               // [2][B][FG][50]
    off += (size_t)NSB * MAXK * sizeof(float);
    int* kcounts = (int*)(ws + off);                       // [2][B][FG]
    off += (size_t)NSB * sizeof(int);
    float* cls_box = (float*)(ws + off);                   // [2][B][FG][4]
    off += (size_t)NSB * 4 * sizeof(float);
    float* best_s = (float*)(ws + off);                    // [2][B][FG]
    off += (size_t)NSB * sizeof(float);
    float* best_b = (float*)(ws + off);                    // [2][B][FG][4]

    nms_kernel<<<NSB, NTH, 0, stream>>>(
        rois_A, cls_A, pred_A, info_A,
        rois_B, cls_B, pred_B, info_B,
        Bimg, N, C, kept_scores, kcounts, cls_box, sync_counter);

    select_combine<<<2 * Bimg, NTH, 0, stream>>>(
        kept_scores, kcounts, cls_box,
        rois_A, pred_A, info_A, rois_B, pred_B, info_B,
        Bimg, N, C, best_s, best_b, sync_counter, out);
}

// Round 4
// 69.682 us; speedup vs baseline: 3.5416x; 1.6918x over previous
//
#include <hip/hip_runtime.h>
#include <stdint.h>
#include <math.h>

#define NTH 64
#define CAP 1024           // max candidates per class (M ~ 300+-16 expected)
#define SLOTS 16           // CAP / 64 register slots per lane
#define MAXK 50
#define THRESH_F 0.05f
#define NMS_T 0.3f

// Decode one (image b, row n, class c) box exactly like the reference:
// bbox_transform_inv + clip + /scale.  (Arithmetic identical to the version
// that passed with absmax 0.0 -- do not reorder.)
__device__ __forceinline__ void decode_box(
    const float* __restrict__ rois, const float* __restrict__ pred,
    float H, float W, float scale,
    int b, int n, int c, int N, int C, float out[4])
{
    const float* r = rois + ((size_t)b * N + n) * 5;
    float bx1 = r[1], by1 = r[2], bx2 = r[3], by2 = r[4];
    float w  = bx2 - bx1 + 1.0f;
    float h  = by2 - by1 + 1.0f;
    float cx = bx1 + 0.5f * w;
    float cy = by1 + 0.5f * h;
    const float* d = pred + ((size_t)b * N + n) * 4 * C + 4 * c;
    float dx = d[0] * 0.1f, dy = d[1] * 0.1f;
    float dw = d[2] * 0.2f, dh = d[3] * 0.2f;
    float pcx = dx * w + cx;
    float pcy = dy * h + cy;
    float pw  = expf(dw) * w;
    float ph  = expf(dh) * h;
    float X1 = fminf(fmaxf(pcx - 0.5f * pw, 0.0f), W - 1.0f);
    float Y1 = fminf(fmaxf(pcy - 0.5f * ph, 0.0f), H - 1.0f);
    float X2 = fminf(fmaxf(pcx + 0.5f * pw, 0.0f), W - 1.0f);
    float Y2 = fminf(fmaxf(pcy + 0.5f * ph, 0.0f), H - 1.0f);
    out[0] = X1 / scale;
    out[1] = Y1 / scale;
    out[2] = X2 / scale;
    out[3] = Y2 / scale;
}

// Register bitonic sort, descending, over SN elements laid out as
// index i = s*64 + lane (slot-major).  Keys are u64 (score<<32|~slot)
// reinterpreted as POSITIVE doubles (exponent field 0x3D4..0x3F8, never
// NaN/denormal), so f64 fmax/fmin ordering == u64 ordering.
// All loops/indices compile-time -> everything stays in VGPRs.
template<int SN>
__device__ __forceinline__ void bitonic_desc(double* kd, int lane)
{
    constexpr int NS = SN / 64;
    #pragma unroll
    for (int k = 2; k <= SN; k <<= 1) {
        #pragma unroll
        for (int j = k >> 1; j >= 1; j >>= 1) {
            if (j >= 64) {
                const int js = j >> 6;
                #pragma unroll
                for (int s = 0; s < NS; ++s) {
                    if ((s & js) == 0) {
                        const int sp = s | js;
                        const bool d = (((s << 6) & k) == 0);  // compile-time
                        const double a = kd[s], bb = kd[sp];
                        kd[s]  = d ? fmax(a, bb) : fmin(a, bb);
                        kd[sp] = d ? fmin(a, bb) : fmax(a, bb);
                    }
                }
            } else {
                #pragma unroll
                for (int s = 0; s < NS; ++s) {
                    const double o = __shfl_xor(kd[s], j);
                    const bool lower = (lane & j) == 0;
                    const bool d = ((((s << 6) | lane) & k) == 0);
                    const bool takeMax = (d == lower);
                    const double mx = fmax(kd[s], o);
                    const double mn = fmin(kd[s], o);
                    kd[s] = takeMax ? mx : mn;
                }
            }
        }
    }
}

// Kernel 1: ONE WAVE per (stream, image, fg-class).
// collect -> decode -> register bitonic sort -> sorted scan NMS
// (64 candidates/batch in lanes; kept set in LDS; scalar ctz keep loop).
__global__ __launch_bounds__(NTH, 1) void nms_kernel(
    const float* __restrict__ rois_A, const float* __restrict__ cls_A,
    const float* __restrict__ pred_A, const float* __restrict__ info_A,
    const float* __restrict__ rois_B, const float* __restrict__ cls_B,
    const float* __restrict__ pred_B, const float* __restrict__ info_B,
    int Bimg, int N, int C,
    float* __restrict__ kept_scores, int* __restrict__ kcounts,
    float* __restrict__ cls_box, int* __restrict__ sync_counter)
{
    const int FG = C - 1;
    const int bx = blockIdx.x;
    const int st  = bx / (Bimg * FG);
    const int rem = bx % (Bimg * FG);
    const int b = rem / FG;
    const int j = rem % FG;
    const int c = j + 1;
    const int lane = threadIdx.x;

    if (bx == 0 && lane == 0) *sync_counter = 0;  // for select_combine

    const float* rois = st ? rois_B : rois_A;
    const float* cls  = st ? cls_B  : cls_A;
    const float* pred = st ? pred_B : pred_A;
    const float* info = st ? info_B : info_A;

    __shared__ unsigned short rowsL[CAP];
    __shared__ float scL[CAP];
    __shared__ float4 boxL[CAP];
    __shared__ uint64_t keysL[CAP];
    __shared__ float4 keptL[MAXK];

    // ---- Collect: ballot-prefix compaction (slot order == row order) ----
    int cnt = 0;
    for (int base = 0; base < N; base += 64) {
        const int n = base + lane;
        float sc = 0.0f;
        if (n < N) sc = cls[((size_t)b * N + n) * C + c];
        const bool val = sc > THRESH_F;
        const uint64_t bal = __ballot(val);
        if (val) {
            const int slot = cnt + __popcll(bal & ((1ull << lane) - 1ull));
            if (slot < CAP) { rowsL[slot] = (unsigned short)n; scL[slot] = sc; }
        }
        cnt += __popcll(bal);
    }
    const int M = cnt < CAP ? cnt : CAP;
    __syncthreads();

    // ---- Decode boxes into LDS; build sort keys in registers ----
    const float H = info[b * 3 + 0];
    const float W = info[b * 3 + 1];
    const float scale = info[b * 3 + 2];
    double kd[SLOTS];
    #pragma unroll
    for (int s = 0; s < SLOTS; ++s) {
        const int slot = s * 64 + lane;
        uint64_t u = 0ull;
        if (slot < M) {
            const int n = rowsL[slot];
            float o[4];
            decode_box(rois, pred, H, W, scale, b, n, c, N, C, o);
            boxL[slot] = make_float4(o[0], o[1], o[2], o[3]);
            u = ((uint64_t)__float_as_uint(scL[slot]) << 32) |
                (uint32_t)(~(uint32_t)slot);
        }
        kd[s] = __longlong_as_double((long long)u);
    }
    __syncthreads();

    // ---- Sort descending (pick smallest sufficient network) ----
    if (M > 1) {
        if (M <= 512) bitonic_desc<512>(kd, lane);
        else          bitonic_desc<1024>(kd, lane);
    }
    // Dump sorted keys to LDS so the scan needs no register-array indexing.
    #pragma unroll
    for (int s = 0; s < SLOTS; ++s)
        keysL[s * 64 + lane] = (uint64_t)__double_as_longlong(kd[s]);
    __syncthreads();

    // ---- Scan NMS over sorted order, 64 candidates per batch ----
    const size_t obase = (size_t)(st * Bimg + b) * FG + j;
    float* ksc = kept_scores + obase * MAXK;
    int kcount = 0;
    float4 cls_best = make_float4(0.f, 0.f, 0.f, 0.f);

    for (int s = 0; s * 64 < M && kcount < MAXK; ++s) {
        const uint64_t u = keysL[s * 64 + lane];
        const bool valid = (u != 0ull);
        float cx1 = 0.f, cy1 = 0.f, cx2 = 0.f, cy2 = 0.f, car = 1.0f, csc = 0.f;
        if (valid) {
            const int slot = (int)(~(uint32_t)u) & (CAP - 1);
            const float4 cb4 = boxL[slot];
            cx1 = cb4.x; cy1 = cb4.y; cx2 = cb4.z; cy2 = cb4.w;
            car = (cx2 - cx1 + 1.0f) * (cy2 - cy1 + 1.0f);
            csc = __uint_as_float((uint32_t)(u >> 32));
        }
        // Pre-suppression vs already-kept boxes (uniform loop, pipelined).
        bool sup = !valid;
        for (int q = 0; q < kcount; ++q) {
            const float4 kb = keptL[q];
            const float kar = (kb.z - kb.x + 1.0f) * (kb.w - kb.y + 1.0f);
            const float ix1 = fmaxf(kb.x, cx1), iy1 = fmaxf(kb.y, cy1);
            const float ix2 = fminf(kb.z, cx2), iy2 = fminf(kb.w, cy2);
            const float iw = fmaxf(ix2 - ix1 + 1.0f, 0.0f);
            const float ih = fmaxf(iy2 - iy1 + 1.0f, 0.0f);
            const float inter = iw * ih;
            sup = sup || (inter / (kar + car - inter) > NMS_T);
        }
        uint64_t alive = ~__ballot(sup);
        // Intra-batch serial keep loop (sorted rank order == lane order).
        while (alive != 0ull && kcount < MAXK) {
            const int l = __builtin_ctzll(alive);      // highest-ranked alive
            const float kx1 = __shfl(cx1, l), ky1 = __shfl(cy1, l);
            const float kx2 = __shfl(cx2, l), ky2 = __shfl(cy2, l);
            const float kar = (kx2 - kx1 + 1.0f) * (ky2 - ky1 + 1.0f);
            if (lane == l) {
                keptL[kcount] = make_float4(cx1, cy1, cx2, cy2);
                ksc[kcount] = csc;
            }
            if (kcount == 0) cls_best = make_float4(kx1, ky1, kx2, ky2);
            const float ix1 = fmaxf(kx1, cx1), iy1 = fmaxf(ky1, cy1);
            const float ix2 = fminf(kx2, cx2), iy2 = fminf(ky2, cy2);
            const float iw = fmaxf(ix2 - ix1 + 1.0f, 0.0f);
            const float ih = fmaxf(iy2 - iy1 + 1.0f, 0.0f);
            const float inter = iw * ih;
            const bool s2 = (inter / (kar + car - inter) > NMS_T);
            alive &= ~__ballot(s2);
            alive &= ~(1ull << l);     // keeper always removed
            kcount++;
        }
    }

    if (lane == 0) {
        kcounts[obase] = kcount;
        float* cbp = cls_box + obase * 4;
        cbp[0] = cls_best.x; cbp[1] = cls_best.y;
        cbp[2] = cls_best.z; cbp[3] = cls_best.w;
    }
}

// Kernel 2: one WAVE per (stream, image): global top-50 cap via branchless
// full count of strictly-greater entries (exact same <50 decision as capped
// counting), then the LAST finished block does the joint A*B argmax.
__global__ __launch_bounds__(NTH) void select_combine(
    const float* __restrict__ kept_scores, const int* __restrict__ kcounts,
    const float* __restrict__ cls_box,
    const float* __restrict__ rois_A, const float* __restrict__ pred_A,
    const float* __restrict__ info_A,
    const float* __restrict__ rois_B, const float* __restrict__ pred_B,
    const float* __restrict__ info_B,
    int Bimg, int N, int C,
    float* best_s, float* best_b, int* sync_counter, float* __restrict__ out)
{
    const int FG = C - 1;
    const int bx = blockIdx.x;           // st*Bimg + b
    const int st = bx / Bimg;
    const int b  = bx % Bimg;
    const int tid = threadIdx.x;

    __shared__ float sk[20][MAXK];
    __shared__ int   skc[20];
    __shared__ float stopv[20];
    __shared__ int   cnt20[20];
    __shared__ int   inflag[20];
    __shared__ float gbox[4];
    __shared__ int   amlast;

    const size_t base = (size_t)bx * FG;
    for (int i = tid; i < FG * MAXK; i += NTH)
        sk[i / MAXK][i % MAXK] = kept_scores[base * MAXK + i];
    if (tid < FG) {
        skc[tid] = kcounts[base + tid];
        cnt20[tid] = 0;
    }
    __syncthreads();
    if (tid < FG)
        stopv[tid] = (skc[tid] > 0) ? sk[tid][0] : -INFINITY;
    __syncthreads();

    // Count entries strictly greater than each class's best (400 pairs over
    // 64 lanes, branchless inner loop -> pipelined LDS reads).
    for (int p = tid; p < FG * FG; p += NTH) {
        const int cc = p / FG;     // candidate class
        const int c2 = p % FG;     // donor class
        const float sc = stopv[cc];
        const int k2 = skc[c2];
        int cnt = 0;
        if (skc[cc] > 0) {
            #pragma unroll 5
            for (int k = 0; k < k2; ++k) {
                const float v = sk[c2][k];
                cnt += ((v > sc) || (v == sc && c2 < cc)) ? 1 : 0;
            }
        }
        if (cnt) atomicAdd(&cnt20[cc], cnt);
    }
    __syncthreads();
    if (tid < FG)
        inflag[tid] = (skc[tid] > 0 && cnt20[tid] < MAXK) ? 1 : 0;
    __syncthreads();

    if (tid == 0) {
        int g = -1;
        float bs = -INFINITY;
        for (int c2 = 0; c2 < FG; ++c2)
            if (skc[c2] > 0 && stopv[c2] > bs) { bs = stopv[c2]; g = c2; }
        if (g >= 0) {
            const float* cbp = cls_box + (base + g) * 4;
            gbox[0] = cbp[0]; gbox[1] = cbp[1]; gbox[2] = cbp[2]; gbox[3] = cbp[3];
        } else {
            const float* rois = st ? rois_B : rois_A;
            const float* pred = st ? pred_B : pred_A;
            const float* info = st ? info_B : info_A;
            decode_box(rois, pred, info[b * 3], info[b * 3 + 1], info[b * 3 + 2],
                       b, 0, 1, N, C, gbox);
        }
    }
    __syncthreads();

    if (tid < FG) {
        const int in = inflag[tid];
        best_s[base + tid] = in ? stopv[tid] : -INFINITY;
        float* ob = best_b + (base + tid) * 4;
        if (in) {
            const float* cbp = cls_box + (base + tid) * 4;
            ob[0] = cbp[0]; ob[1] = cbp[1]; ob[2] = cbp[2]; ob[3] = cbp[3];
        } else {
            ob[0] = gbox[0]; ob[1] = gbox[1]; ob[2] = gbox[2]; ob[3] = gbox[3];
        }
    }

    // ---- last-done block performs the combine ----
    __threadfence();
    if (tid == 0) amlast = (atomicAdd(sync_counter, 1) == 2 * Bimg - 1);
    __syncthreads();
    if (amlast) {
        __threadfence();   // acquire: other blocks' best_s/best_b now visible
        if (tid < Bimg) {
            const int i = tid;
            const float* sA = best_s + (size_t)i * FG;
            const float* sB = best_s + (size_t)(Bimg + i) * FG;
            float bj = 0.0f;
            int cls = 0;
            for (int cc = 0; cc < FG; ++cc) {
                const float v = sA[cc] * sB[cc];   // IEEE: -inf*-inf=+inf
                if (cc == 0 || v > bj) { bj = v; cls = cc; }
            }
            const float* bA = best_b + ((size_t)i * FG + cls) * 4;
            const float* bB = best_b + ((size_t)(Bimg + i) * FG + cls) * 4;
            for (int k = 0; k < 4; ++k) {
                out[i * 4 + k]            = bA[k];
                out[Bimg * 4 + i * 4 + k] = bB[k];
            }
        }
    }
}

extern "C" void kernel_launch(void* const* d_in, const int* in_sizes, int n_in,
                              void* d_out, int out_size, void* d_ws, size_t ws_size,
                              hipStream_t stream) {
    const float* rois_A = (const float*)d_in[0];
    const float* cls_A  = (const float*)d_in[1];
    const float* pred_A = (const float*)d_in[2];
    const float* info_A = (const float*)d_in[3];
    const float* rois_B = (const float*)d_in[4];
    const float* cls_B  = (const float*)d_in[5];
    const float* pred_B = (const float*)d_in[6];
    const float* info_B = (const float*)d_in[7];
    float* out = (float*)d_out;

    const int Bimg = in_sizes[3] / 3;                  // 8
    const int N    = in_sizes[0] / (Bimg * 5);         // 2000
    const int C    = in_sizes[1] / (Bimg * N);         // 21
    const int FG   = C - 1;                            // 20
    const int NSB  = 2 * Bimg * FG;                    // 320 tasks

    char* ws = (char*)d_ws;
    int* sync_counter = (int*)ws;
    size_t off = 16;
    float* kept_scores = (float*)(ws + off);               // [2][B][FG][50]
    off += (size_t)NSB * MAXK * sizeof(float);
    int* kcounts = (int*)(ws + off);                       // [2][B][FG]
    off += (size_t)NSB * sizeof(int);
    float* cls_box = (float*)(ws + off);                   // [2][B][FG][4]
    off += (size_t)NSB * 4 * sizeof(float);
    float* best_s = (float*)(ws + off);                    // [2][B][FG]
    off += (size_t)NSB * sizeof(float);
    float* best_b = (float*)(ws + off);                    // [2][B][FG][4]

    nms_kernel<<<NSB, NTH, 0, stream>>>(
        rois_A, cls_A, pred_A, info_A,
        rois_B, cls_B, pred_B, info_B,
        Bimg, N, C, kept_scores, kcounts, cls_box, sync_counter);

    select_combine<<<2 * Bimg, NTH, 0, stream>>>(
        kept_scores, kcounts, cls_box,
        rois_A, pred_A, info_A, rois_B, pred_B, info_B,
        Bimg, N, C, best_s, best_b, sync_counter, out);
}